// Round 4
// baseline (411.572 us; speedup 1.0000x reference)
//
#include <hip/hip_runtime.h>

// ViewMorphing forward — MI355X (gfx950)
// out[0 .. 3*N*HW-1] = warped+masked image sum, out[3*N*HW] = oob loss scalar.
//
// v4: latency/MLP-bound (R3: FETCH fixed at 164MB, dur stuck ~194us, VALU 11%,
//     VGPR=60 -> compiler serialized tap loads to hit 8-waves/SIMD budget).
//  - __launch_bounds__(256,4): allow ~128 VGPR, trade occupancy for MLP.
//  - explicit 2-stage pipeline: issue pixel j+1's 24 tap loads (both images)
//    before consuming pixel j's -> ~24-48 loads in flight per wave.
//  - keeps v3: XCD slab swizzle, saddr bases, NT stream loads/stores.

constexpr int D    = 512;
constexpr int HW   = D * D;            // 262144 = 2^18
constexpr int NB   = 32;
constexpr int NPIX = NB * HW;          // 8,388,608
// loss scale: 0.01 / (N*2*HW) / (D*D)
constexpr float LOSS_SCALE = (float)(0.01 / (2.0 * (double)NPIX * (double)HW));

typedef float f4 __attribute__((ext_vector_type(4)));

struct Samp {
    float v00[3], v01[3], v10[3], v11[3];   // taps per channel
    float ax, ay, sc;
};

// Phase A: compute coords, accumulate oob, ISSUE the 12 tap loads.
__device__ __forceinline__ void issue_sample(const float* __restrict__ p,
                                             float q0o, float q1o,
                                             float& oob, Samp& S)
{
    const float hi = 510.999f;                  // D - 1.001
    float q0 = fminf(fmaxf(q0o, 0.001f), hi);
    float q1 = fminf(fmaxf(q1o, 0.001f), hi);
    float d0 = q0o - q0, d1 = q1o - q1;
    oob = fmaf(d0, d0, oob);
    oob = fmaf(d1, d1, oob);

    float fx = floorf(q0), fy = floorf(q1);
    S.ax = q0 - fx;
    S.ay = q1 - fy;
    // reference ceil==floor case: coincident taps, weights sum to 2
    S.sc = ((S.ax == 0.0f) ? 2.0f : 1.0f) * ((S.ay == 0.0f) ? 2.0f : 1.0f);

    // ind = y + D*x ; q<=510.999 -> +1 row/col always in bounds
    int off = (int)fy + (((int)fx) << 9);

    #pragma unroll
    for (int c = 0; c < 3; ++c) {
        const float* pc = p + c * HW + off;     // SGPR base + VGPR offset
        S.v00[c] = pc[0];
        S.v01[c] = pc[1];
        S.v10[c] = pc[512];
        S.v11[c] = pc[513];
    }
}

// Phase B: consume the loaded taps.
__device__ __forceinline__ float3 finish_sample(const Samp& S)
{
    float r[3];
    #pragma unroll
    for (int c = 0; c < 3; ++c) {
        float top = fmaf(S.ay, S.v01[c] - S.v00[c], S.v00[c]);
        float bot = fmaf(S.ay, S.v11[c] - S.v10[c], S.v10[c]);
        r[c] = fmaf(S.ax, bot - top, top);
    }
    return make_float3(r[0], r[1], r[2]);
}

__global__ void __launch_bounds__(256, 4)
vm_fwd(const float* __restrict__ im1, const float* __restrict__ im2,
       const float* __restrict__ C,   const float* __restrict__ M1,
       const float* __restrict__ M2,  float* __restrict__ out)
{
    // XCD slab swizzle: 8192 blocks; b&7 selects the XCD on dispatch, so give
    // XCD x the contiguous slab [x*1024,(x+1)*1024) = 4 whole images.
    // Bijective: 8192 = 8 * 1024 exactly.
    const int b    = blockIdx.x;
    const int slab = ((b & 7) << 10) | (b >> 3);

    // 1024 consecutive pixels per slab-block -> n, image bases block-uniform.
    const int n  = slab >> 8;
    const int hw = ((slab & 255) << 10) | (threadIdx.x << 2);

    const float qx  = (float)(hw >> 9);         // row (same for all 4 px)
    const float qy0 = (float)(hw & 511);        // first col

    const float* Cn = C   + (size_t)n * 2 * HW;
    const float* Mp = M1  + (size_t)n * HW;
    const float* Mq = M2  + (size_t)n * HW;
    const float* p1 = im1 + (size_t)n * 3 * HW;
    const float* p2 = im2 + (size_t)n * 3 * HW;

    // pure streams, never re-read: nontemporal -> don't evict tap lines
    f4 c0 = __builtin_nontemporal_load((const f4*)(Cn + hw));
    f4 c1 = __builtin_nontemporal_load((const f4*)(Cn + HW + hw));
    f4 m1 = __builtin_nontemporal_load((const f4*)(Mp + hw));
    f4 m2 = __builtin_nontemporal_load((const f4*)(Mq + hw));

    float oob = 0.0f;
    float o0a[4], o1a[4], o2a[4];

    // 2-stage pipeline: issue j+1's loads before finishing j.
    // All indices compile-time after unroll (no scratch).
    Samp SA[2], SB[2];
    issue_sample(p1, qx + c0[0], qy0 + c1[0], oob, SA[0]);
    issue_sample(p2, qx - c0[0], qy0 - c1[0], oob, SB[0]);

    #pragma unroll
    for (int j = 0; j < 4; ++j) {
        if (j < 3) {
            float qyj = qy0 + (float)(j + 1);
            issue_sample(p1, qx + c0[j + 1], qyj + c1[j + 1], oob, SA[(j + 1) & 1]);
            issue_sample(p2, qx - c0[j + 1], qyj - c1[j + 1], oob, SB[(j + 1) & 1]);
        }
        float3 av = finish_sample(SA[j & 1]);
        float3 bv = finish_sample(SB[j & 1]);
        float w1 = m1[j] * SA[j & 1].sc;
        float w2 = m2[j] * SB[j & 1].sc;
        o0a[j] = fmaf(av.x, w1, bv.x * w2);
        o1a[j] = fmaf(av.y, w1, bv.y * w2);
        o2a[j] = fmaf(av.z, w1, bv.z * w2);
    }

    f4 o0 = {o0a[0], o0a[1], o0a[2], o0a[3]};
    f4 o1 = {o1a[0], o1a[1], o1a[2], o1a[3]};
    f4 o2 = {o2a[0], o2a[1], o2a[2], o2a[3]};

    size_t obase = (size_t)n * 3 * HW + hw;
    // streaming outputs: never re-read -> keep L2 for the gather taps
    __builtin_nontemporal_store(o0, (f4*)(out + obase));
    __builtin_nontemporal_store(o1, (f4*)(out + obase + HW));
    __builtin_nontemporal_store(o2, (f4*)(out + obase + 2 * HW));

    // block-level reduction of oob, then one atomic per block
    #pragma unroll
    for (int off = 32; off > 0; off >>= 1)
        oob += __shfl_down(oob, off, 64);

    __shared__ float wave_sums[4];   // 256 threads / wave64
    int lane = threadIdx.x & 63;
    int wave = threadIdx.x >> 6;
    if (lane == 0) wave_sums[wave] = oob;
    __syncthreads();
    if (threadIdx.x == 0) {
        float s = wave_sums[0] + wave_sums[1] + wave_sums[2] + wave_sums[3];
        atomicAdd(out + (size_t)3 * NPIX, s * LOSS_SCALE);
    }
}

extern "C" void kernel_launch(void* const* d_in, const int* in_sizes, int n_in,
                              void* d_out, int out_size, void* d_ws, size_t ws_size,
                              hipStream_t stream) {
    const float* im1 = (const float*)d_in[0];
    const float* im2 = (const float*)d_in[1];
    const float* C   = (const float*)d_in[2];
    const float* M1  = (const float*)d_in[3];
    const float* M2  = (const float*)d_in[4];
    float* out = (float*)d_out;

    // zero the loss scalar (harness poisons d_out with 0xAA before every launch)
    hipMemsetAsync(out + (size_t)3 * NPIX, 0, sizeof(float), stream);

    // NPIX / (256 threads * 4 px) = 8192 blocks, exact cover
    vm_fwd<<<8192, 256, 0, stream>>>(im1, im2, C, M1, M2, out);
}

// Round 5
// 371.803 us; speedup vs baseline: 1.1070x; 1.1070x over previous
//
#include <hip/hip_runtime.h>

// ViewMorphing forward — MI355X (gfx950)
// out[0 .. 3*N*HW-1] = warped+masked image sum, out[3*N*HW] = oob loss scalar.
//
// v5: address-divergence bound. R4 showed ~37 cyc per gather instr = ~36
//     distinct 128B lines touched per wave64 tap load (lane i owned 4
//     consecutive pixels -> wave spans 256 cols x ~4 random rows).
//     Remap: thread t takes pixels hw0 + t + j*256 -> each tap instruction
//     spans 64 consecutive cols (+-2) x ~5 rows ~= 9-13 lines, 3-4x fewer
//     line transactions on the saturated TA/L1 pipe.
//  - C/M loads + out stores become scalar but stay perfectly coalesced
//    (256B per wave instruction).
//  - dropped v4's source-level pipeline + launch_bounds waves hint (both
//    measured no-ops; compiler re-schedules anyway).
//  - keeps v3: XCD slab swizzle, block-uniform saddr image bases, NT streams.

constexpr int D    = 512;
constexpr int HW   = D * D;            // 262144 = 2^18
constexpr int NB   = 32;
constexpr int NPIX = NB * HW;          // 8,388,608
// loss scale: 0.01 / (N*2*HW) / (D*D)
constexpr float LOSS_SCALE = (float)(0.01 / (2.0 * (double)NPIX * (double)HW));

// Bilinear 3-channel sample from image base p (block-uniform -> SGPR base).
// Accumulates oob penalty; wscale carries the reference's weight-doubling
// factor for exactly-integral coordinates (where ceil==floor).
__device__ __forceinline__ float3 sample3(const float* __restrict__ p,
                                          float q0o, float q1o,
                                          float& oob, float& wscale)
{
    const float hi = 510.999f;                  // D - 1.001
    float q0 = fminf(fmaxf(q0o, 0.001f), hi);
    float q1 = fminf(fmaxf(q1o, 0.001f), hi);
    float d0 = q0o - q0, d1 = q1o - q1;
    oob = fmaf(d0, d0, oob);
    oob = fmaf(d1, d1, oob);

    float fx = floorf(q0), fy = floorf(q1);
    float ax = q0 - fx,    ay = q1 - fy;        // in [0,1)
    // reference: when coord exactly integral, floor- and ceil-taps coincide
    // and their weights sum to 2 -> fold into wscale.
    wscale = ((ax == 0.0f) ? 2.0f : 1.0f) * ((ay == 0.0f) ? 2.0f : 1.0f);

    // ind = y + D*x ; q<=510.999 -> +1 row/col always in bounds.
    int off = (int)fy + (((int)fx) << 9);

    float r[3];
    #pragma unroll
    for (int c = 0; c < 3; ++c) {
        const float* pc = p + c * HW;           // uniform + uniform: stays SGPR
        float v00 = pc[off];
        float v01 = pc[off + 1];
        float v10 = pc[off + 512];
        float v11 = pc[off + 513];
        float top = fmaf(ay, v01 - v00, v00);
        float bot = fmaf(ay, v11 - v10, v10);
        r[c] = fmaf(ax, bot - top, top);
    }
    return make_float3(r[0], r[1], r[2]);
}

__global__ void __launch_bounds__(256)
vm_fwd(const float* __restrict__ im1, const float* __restrict__ im2,
       const float* __restrict__ C,   const float* __restrict__ M1,
       const float* __restrict__ M2,  float* __restrict__ out)
{
    // XCD slab swizzle: 8192 blocks; b&7 selects the XCD on dispatch, so give
    // XCD x the contiguous slab [x*1024,(x+1)*1024) = 4 whole images.
    // Bijective: 8192 = 8 * 1024 exactly.
    const int b    = blockIdx.x;
    const int slab = ((b & 7) << 10) | (b >> 3);

    // Block owns 1024 consecutive pixels -> n, image bases block-uniform.
    // Thread t handles pixels hw0 + j*256 (j=0..3): each wave instruction
    // covers 64 CONSECUTIVE pixels -> minimal line footprint on gathers.
    const int n   = slab >> 8;
    const int hw0 = ((slab & 255) << 10) | threadIdx.x;

    const float* Cn = C   + (size_t)n * 2 * HW;
    const float* Mp = M1  + (size_t)n * HW;
    const float* Mq = M2  + (size_t)n * HW;
    const float* p1 = im1 + (size_t)n * 3 * HW;
    const float* p2 = im2 + (size_t)n * 3 * HW;
    float* op       = out + (size_t)n * 3 * HW;

    float oob = 0.0f;

    #pragma unroll
    for (int j = 0; j < 4; ++j) {
        const int hw = hw0 + j * 256;
        const float qx = (float)(hw >> 9);
        const float qy = (float)(hw & 511);

        // pure streams, never re-read: nontemporal -> don't evict tap lines
        float c0 = __builtin_nontemporal_load(Cn + hw);
        float c1 = __builtin_nontemporal_load(Cn + HW + hw);
        float m1 = __builtin_nontemporal_load(Mp + hw);
        float m2 = __builtin_nontemporal_load(Mq + hw);

        float sA, sB;
        float3 av = sample3(p1, qx + c0, qy + c1, oob, sA);
        float3 bv = sample3(p2, qx - c0, qy - c1, oob, sB);
        float w1 = m1 * sA;
        float w2 = m2 * sB;

        // coalesced 256B scalar stores, streaming
        __builtin_nontemporal_store(fmaf(av.x, w1, bv.x * w2), op + hw);
        __builtin_nontemporal_store(fmaf(av.y, w1, bv.y * w2), op + HW + hw);
        __builtin_nontemporal_store(fmaf(av.z, w1, bv.z * w2), op + 2 * HW + hw);
    }

    // block-level reduction of oob, then one atomic per block
    #pragma unroll
    for (int off = 32; off > 0; off >>= 1)
        oob += __shfl_down(oob, off, 64);

    __shared__ float wave_sums[4];   // 256 threads / wave64
    int lane = threadIdx.x & 63;
    int wave = threadIdx.x >> 6;
    if (lane == 0) wave_sums[wave] = oob;
    __syncthreads();
    if (threadIdx.x == 0) {
        float s = wave_sums[0] + wave_sums[1] + wave_sums[2] + wave_sums[3];
        atomicAdd(out + (size_t)3 * NPIX, s * LOSS_SCALE);
    }
}

extern "C" void kernel_launch(void* const* d_in, const int* in_sizes, int n_in,
                              void* d_out, int out_size, void* d_ws, size_t ws_size,
                              hipStream_t stream) {
    const float* im1 = (const float*)d_in[0];
    const float* im2 = (const float*)d_in[1];
    const float* C   = (const float*)d_in[2];
    const float* M1  = (const float*)d_in[3];
    const float* M2  = (const float*)d_in[4];
    float* out = (float*)d_out;

    // zero the loss scalar (harness poisons d_out with 0xAA before every launch)
    hipMemsetAsync(out + (size_t)3 * NPIX, 0, sizeof(float), stream);

    // NPIX / (256 threads * 4 px) = 8192 blocks, exact cover
    vm_fwd<<<8192, 256, 0, stream>>>(im1, im2, C, M1, M2, out);
}

// Round 6
// 367.953 us; speedup vs baseline: 1.1185x; 1.0105x over previous
//
#include <hip/hip_runtime.h>

// ViewMorphing forward — MI355X (gfx950)
// out[0 .. 3*N*HW-1] = warped+masked image sum, out[3*N*HW] = oob loss scalar.
//
// v6: gather-instruction-count bound. R4/R5 data fit cost-per-gather =
//     ~16 cyc fixed (64 divergent lane addrs) + ~1 cyc/line; 12,288 gathers
//     x 31 cyc = 100% of v5's CU time. Lines are near-minimal -> cut the
//     INSTRUCTION count: taps are horizontally adjacent pairs, so load each
//     pair as one 8-byte load (96 -> 48 gathers/thread).
//     off is only 4B-aligned -> __builtin_memcpy into float2: emits
//     global_load_dwordx2 if gfx950 unaligned mode allows, else legalizes
//     to 2x dword (= v5, zero correctness risk either way).
//  - keeps v5: consecutive-pixel thread mapping, XCD slab swizzle,
//    block-uniform saddr bases, NT stream loads/stores.

constexpr int D    = 512;
constexpr int HW   = D * D;            // 262144 = 2^18
constexpr int NB   = 32;
constexpr int NPIX = NB * HW;          // 8,388,608
// loss scale: 0.01 / (N*2*HW) / (D*D)
constexpr float LOSS_SCALE = (float)(0.01 / (2.0 * (double)NPIX * (double)HW));

// Bilinear 3-channel sample from image base p (block-uniform -> SGPR base).
// Accumulates oob penalty; wscale carries the reference's weight-doubling
// factor for exactly-integral coordinates (where ceil==floor).
__device__ __forceinline__ float3 sample3(const float* __restrict__ p,
                                          float q0o, float q1o,
                                          float& oob, float& wscale)
{
    const float hi = 510.999f;                  // D - 1.001
    float q0 = fminf(fmaxf(q0o, 0.001f), hi);
    float q1 = fminf(fmaxf(q1o, 0.001f), hi);
    float d0 = q0o - q0, d1 = q1o - q1;
    oob = fmaf(d0, d0, oob);
    oob = fmaf(d1, d1, oob);

    float fx = floorf(q0), fy = floorf(q1);
    float ax = q0 - fx,    ay = q1 - fy;        // in [0,1)
    // reference: when coord exactly integral, floor- and ceil-taps coincide
    // and their weights sum to 2 -> fold into wscale.
    wscale = ((ax == 0.0f) ? 2.0f : 1.0f) * ((ay == 0.0f) ? 2.0f : 1.0f);

    // ind = y + D*x ; q<=510.999 -> +1 row/col always in bounds.
    int off = (int)fy + (((int)fx) << 9);

    float r[3];
    #pragma unroll
    for (int c = 0; c < 3; ++c) {
        const float* pc = p + c * HW + off;     // SGPR base + VGPR offset
        float2 t, bo;                           // {v00,v01}, {v10,v11}
        __builtin_memcpy(&t,  pc,       8);     // cols (fy, fy+1), row fx
        __builtin_memcpy(&bo, pc + 512, 8);     // cols (fy, fy+1), row fx+1
        float top = fmaf(ay, t.y  - t.x,  t.x);
        float bot = fmaf(ay, bo.y - bo.x, bo.x);
        r[c] = fmaf(ax, bot - top, top);
    }
    return make_float3(r[0], r[1], r[2]);
}

__global__ void __launch_bounds__(256)
vm_fwd(const float* __restrict__ im1, const float* __restrict__ im2,
       const float* __restrict__ C,   const float* __restrict__ M1,
       const float* __restrict__ M2,  float* __restrict__ out)
{
    // XCD slab swizzle: 8192 blocks; b&7 selects the XCD on dispatch, so give
    // XCD x the contiguous slab [x*1024,(x+1)*1024) = 4 whole images.
    // Bijective: 8192 = 8 * 1024 exactly.
    const int b    = blockIdx.x;
    const int slab = ((b & 7) << 10) | (b >> 3);

    // Block owns 1024 consecutive pixels; thread t handles hw0 + j*256:
    // each wave instruction covers 64 CONSECUTIVE pixels -> minimal line
    // footprint on the divergent gathers.
    const int n   = slab >> 8;
    const int hw0 = ((slab & 255) << 10) | threadIdx.x;

    const float* Cn = C   + (size_t)n * 2 * HW;
    const float* Mp = M1  + (size_t)n * HW;
    const float* Mq = M2  + (size_t)n * HW;
    const float* p1 = im1 + (size_t)n * 3 * HW;
    const float* p2 = im2 + (size_t)n * 3 * HW;
    float* op       = out + (size_t)n * 3 * HW;

    float oob = 0.0f;

    #pragma unroll
    for (int j = 0; j < 4; ++j) {
        const int hw = hw0 + j * 256;
        const float qx = (float)(hw >> 9);
        const float qy = (float)(hw & 511);

        // pure streams, never re-read: nontemporal -> don't evict tap lines
        float c0 = __builtin_nontemporal_load(Cn + hw);
        float c1 = __builtin_nontemporal_load(Cn + HW + hw);
        float m1 = __builtin_nontemporal_load(Mp + hw);
        float m2 = __builtin_nontemporal_load(Mq + hw);

        float sA, sB;
        float3 av = sample3(p1, qx + c0, qy + c1, oob, sA);
        float3 bv = sample3(p2, qx - c0, qy - c1, oob, sB);
        float w1 = m1 * sA;
        float w2 = m2 * sB;

        // coalesced 256B scalar stores, streaming
        __builtin_nontemporal_store(fmaf(av.x, w1, bv.x * w2), op + hw);
        __builtin_nontemporal_store(fmaf(av.y, w1, bv.y * w2), op + HW + hw);
        __builtin_nontemporal_store(fmaf(av.z, w1, bv.z * w2), op + 2 * HW + hw);
    }

    // block-level reduction of oob, then one atomic per block
    #pragma unroll
    for (int off = 32; off > 0; off >>= 1)
        oob += __shfl_down(oob, off, 64);

    __shared__ float wave_sums[4];   // 256 threads / wave64
    int lane = threadIdx.x & 63;
    int wave = threadIdx.x >> 6;
    if (lane == 0) wave_sums[wave] = oob;
    __syncthreads();
    if (threadIdx.x == 0) {
        float s = wave_sums[0] + wave_sums[1] + wave_sums[2] + wave_sums[3];
        atomicAdd(out + (size_t)3 * NPIX, s * LOSS_SCALE);
    }
}

extern "C" void kernel_launch(void* const* d_in, const int* in_sizes, int n_in,
                              void* d_out, int out_size, void* d_ws, size_t ws_size,
                              hipStream_t stream) {
    const float* im1 = (const float*)d_in[0];
    const float* im2 = (const float*)d_in[1];
    const float* C   = (const float*)d_in[2];
    const float* M1  = (const float*)d_in[3];
    const float* M2  = (const float*)d_in[4];
    float* out = (float*)d_out;

    // zero the loss scalar (harness poisons d_out with 0xAA before every launch)
    hipMemsetAsync(out + (size_t)3 * NPIX, 0, sizeof(float), stream);

    // NPIX / (256 threads * 4 px) = 8192 blocks, exact cover
    vm_fwd<<<8192, 256, 0, stream>>>(im1, im2, C, M1, M2, out);
}

// Round 7
// 340.087 us; speedup vs baseline: 1.2102x; 1.0819x over previous
//
#include <hip/hip_runtime.h>

// ViewMorphing forward — MI355X (gfx950)
// out[0 .. 3*N*HW-1] = warped+masked image sum, out[3*N*HW] = oob loss scalar.
//
// v7: LDS-windowed gather. R4-R6 established a ~30-cyc fixed cost per
//     divergent wave64 GLOBAL gather (TA address processing), instruction-
//     count bound; compiler refuses wider unaligned gathers. So move the
//     divergent access to LDS, which handles per-lane random addressing
//     natively (banked, ~6-15 cyc). Block owns pixel rows {r,r+1}; taps lie
//     in rows [r-3,r+4] with P=99.86%/sample -> stage that 8-row x 3-ch
//     window (48KB) and bilinear-tap from LDS; rare out-of-window samples
//     take a divergent global fallback (identical math). Two phases (im1,
//     im2) reuse one buffer to fit 64KB/WG.
//  - keeps: consecutive-pixel mapping, XCD slab swizzle, saddr bases,
//    NT stream loads / NT stores, identical interp formulas (absmax-stable).

constexpr int D    = 512;
constexpr int HW   = D * D;            // 262144 = 2^18
constexpr int NB   = 32;
constexpr int NPIX = NB * HW;          // 8,388,608
// loss scale: 0.01 / (N*2*HW) / (D*D)
constexpr float LOSS_SCALE = (float)(0.01 / (2.0 * (double)NPIX * (double)HW));

typedef float f4 __attribute__((ext_vector_type(4)));

// LDS window: [ch][row-slot u:8][col:512]  = 24*512 floats = 49,152 B
constexpr int WROWS = 8;
constexpr int LDSZ  = 3 * WROWS * 512;

__device__ __forceinline__ float lerp2(float v00, float v01, float v10, float v11,
                                       float ax, float ay)
{
    float top = fmaf(ay, v01 - v00, v00);
    float bot = fmaf(ay, v11 - v10, v10);
    return fmaf(ax, bot - top, top);
}

struct Coord { float ax, ay, sc; int off; int u; bool in; };

__device__ __forceinline__ Coord make_coord(float q0o, float q1o, int wlo, float& oob)
{
    const float hi = 510.999f;                  // D - 1.001
    float q0 = fminf(fmaxf(q0o, 0.001f), hi);
    float q1 = fminf(fmaxf(q1o, 0.001f), hi);
    float d0 = q0o - q0, d1 = q1o - q1;
    oob = fmaf(d0, d0, oob);
    oob = fmaf(d1, d1, oob);

    float fx = floorf(q0), fy = floorf(q1);
    Coord c;
    c.ax = q0 - fx;
    c.ay = q1 - fy;
    // reference ceil==floor case: coincident taps, weights sum to 2
    c.sc = ((c.ax == 0.0f) ? 2.0f : 1.0f) * ((c.ay == 0.0f) ? 2.0f : 1.0f);
    int ix = (int)fx, iy = (int)fy;
    c.off = iy + (ix << 9);                     // global flat index (row-major)
    c.u   = ix - wlo;                           // LDS row-slot
    c.in  = (unsigned)c.u <= (unsigned)(WROWS - 2);   // u in [0,6] -> u,u+1 staged
    return c;
}

// Sample 3 channels: LDS window if in, else global fallback (same formula).
__device__ __forceinline__ float3 sample_win(const float* __restrict__ lds,
                                             const float* __restrict__ p,
                                             const Coord& c)
{
    float r0, r1, r2;
    if (c.in) {
        int base = (c.u << 9) + (c.off & 511);  // [u][col], ch-plane stride 4096
        float a00 = lds[base],        a01 = lds[base + 1];
        float a10 = lds[base + 512],  a11 = lds[base + 513];
        r0 = lerp2(a00, a01, a10, a11, c.ax, c.ay);
        float b00 = lds[base + 4096], b01 = lds[base + 4097];
        float b10 = lds[base + 4608], b11 = lds[base + 4609];
        r1 = lerp2(b00, b01, b10, b11, c.ax, c.ay);
        float c00 = lds[base + 8192], c01 = lds[base + 8193];
        float c10 = lds[base + 8704], c11 = lds[base + 8705];
        r2 = lerp2(c00, c01, c10, c11, c.ax, c.ay);
    } else {
        const float* pc = p + c.off;
        r0 = lerp2(pc[0],        pc[1],        pc[512],        pc[513],        c.ax, c.ay);
        r1 = lerp2(pc[HW],       pc[HW + 1],   pc[HW + 512],   pc[HW + 513],   c.ax, c.ay);
        r2 = lerp2(pc[2 * HW],   pc[2*HW + 1], pc[2*HW + 512], pc[2*HW + 513], c.ax, c.ay);
    }
    return make_float3(r0, r1, r2);
}

// Stage rows [wlo, wlo+7] x 3ch of img into lds. Coalesced f4, linear LDS.
__device__ __forceinline__ void stage(float* __restrict__ lds,
                                      const float* __restrict__ img,
                                      int wlo, int tid)
{
    #pragma unroll
    for (int q = 0; q < 12; ++q) {
        int e4    = q * 256 + tid;              // f4 index, 0..3071
        int plane = e4 >> 7;                    // (ch<<3)|u, 0..23
        int ch    = plane >> 3;
        int u     = plane & 7;
        int col   = (e4 & 127) << 2;
        f4 v = *(const f4*)(img + (size_t)ch * HW + ((wlo + u) << 9) + col);
        *(f4*)(lds + (plane << 9) + col) = v;   // linear: plane*512 + col
    }
}

__global__ void __launch_bounds__(256)
vm_fwd(const float* __restrict__ im1, const float* __restrict__ im2,
       const float* __restrict__ C,   const float* __restrict__ M1,
       const float* __restrict__ M2,  float* __restrict__ out)
{
    __shared__ float lds[LDSZ];

    // XCD slab swizzle (bijective: 8192 = 8*1024): XCD x owns 4 whole images.
    const int b    = blockIdx.x;
    const int slab = ((b & 7) << 10) | (b >> 3);

    const int n   = slab >> 8;
    const int k   = slab & 255;                 // row-pair index within image
    const int r   = k << 1;                     // first owned pixel row
    const int tid = threadIdx.x;
    const int hw0 = (k << 10) | tid;
    const int wlo = min(max(r - 3, 0), D - WROWS);   // staged-window first row

    const float* Cn = C   + (size_t)n * 2 * HW;
    const float* Mp = M1  + (size_t)n * HW;
    const float* Mq = M2  + (size_t)n * HW;
    const float* p1 = im1 + (size_t)n * 3 * HW;
    const float* p2 = im2 + (size_t)n * 3 * HW;
    float* op       = out + (size_t)n * 3 * HW;

    // stream inputs (never re-read): NT scalar, 256B/wave-instr coalesced
    float c0v[4], c1v[4], m1v[4], m2v[4];
    #pragma unroll
    for (int j = 0; j < 4; ++j) {
        int hw = hw0 + j * 256;
        c0v[j] = __builtin_nontemporal_load(Cn + hw);
        c1v[j] = __builtin_nontemporal_load(Cn + HW + hw);
        m1v[j] = __builtin_nontemporal_load(Mp + hw);
        m2v[j] = __builtin_nontemporal_load(Mq + hw);
    }

    float oob = 0.0f;

    // ---- phase A: im1 ----
    stage(lds, p1, wlo, tid);
    __syncthreads();
    float a0[4], a1[4], a2[4];
    #pragma unroll
    for (int j = 0; j < 4; ++j) {
        int hw = hw0 + j * 256;
        float qx = (float)(hw >> 9), qy = (float)(hw & 511);
        Coord cc = make_coord(qx + c0v[j], qy + c1v[j], wlo, oob);
        float3 av = sample_win(lds, p1, cc);
        float w1 = m1v[j] * cc.sc;
        a0[j] = av.x * w1; a1[j] = av.y * w1; a2[j] = av.z * w1;
    }
    __syncthreads();

    // ---- phase B: im2, combine + store ----
    stage(lds, p2, wlo, tid);
    __syncthreads();
    #pragma unroll
    for (int j = 0; j < 4; ++j) {
        int hw = hw0 + j * 256;
        float qx = (float)(hw >> 9), qy = (float)(hw & 511);
        Coord cc = make_coord(qx - c0v[j], qy - c1v[j], wlo, oob);
        float3 bv = sample_win(lds, p2, cc);
        float w2 = m2v[j] * cc.sc;
        __builtin_nontemporal_store(fmaf(bv.x, w2, a0[j]), op + hw);
        __builtin_nontemporal_store(fmaf(bv.y, w2, a1[j]), op + HW + hw);
        __builtin_nontemporal_store(fmaf(bv.z, w2, a2[j]), op + 2 * HW + hw);
    }

    // block-level reduction of oob, then one atomic per block
    #pragma unroll
    for (int off = 32; off > 0; off >>= 1)
        oob += __shfl_down(oob, off, 64);

    __shared__ float wave_sums[4];   // 256 threads / wave64
    int lane = tid & 63;
    int wave = tid >> 6;
    if (lane == 0) wave_sums[wave] = oob;
    __syncthreads();
    if (tid == 0) {
        float s = wave_sums[0] + wave_sums[1] + wave_sums[2] + wave_sums[3];
        atomicAdd(out + (size_t)3 * NPIX, s * LOSS_SCALE);
    }
}

extern "C" void kernel_launch(void* const* d_in, const int* in_sizes, int n_in,
                              void* d_out, int out_size, void* d_ws, size_t ws_size,
                              hipStream_t stream) {
    const float* im1 = (const float*)d_in[0];
    const float* im2 = (const float*)d_in[1];
    const float* C   = (const float*)d_in[2];
    const float* M1  = (const float*)d_in[3];
    const float* M2  = (const float*)d_in[4];
    float* out = (float*)d_out;

    // zero the loss scalar (harness poisons d_out with 0xAA before every launch)
    hipMemsetAsync(out + (size_t)3 * NPIX, 0, sizeof(float), stream);

    // NPIX / (256 threads * 4 px) = 8192 blocks, exact cover
    vm_fwd<<<8192, 256, 0, stream>>>(im1, im2, C, M1, M2, out);
}